// Round 9
// baseline (36.497 us; speedup 1.0000x reference)
//
#include <hip/hip_runtime.h>
#include <hip/hip_bf16.h>

// Problem constants (fixed by the reference file):
//   B=16 docs, PREV(K)=768, D(N)=256, lengths[i]=1024+128*i, T=31744, MAXLEN=2944
// Doc start offsets are multiples of 128 -> 32-row M-tiles never straddle docs.
// Per-doc padding 1920-128*d is a multiple of 64 -> 64-row zero tiles never straddle.

#define T_TOTAL 31744
#define K_DIM   768
#define N_DIM   256
#define MAXLEN  2944
#define NKT     24          // K_DIM / 32
#define NGEMM   992         // T_TOTAL / 32
#define NZERO   240         // 15360 padding rows / 64

typedef __attribute__((ext_vector_type(8))) short    bf16x8;
typedef __attribute__((ext_vector_type(4))) float    f32x4;
typedef __attribute__((ext_vector_type(4))) unsigned u32x4;

__device__ __forceinline__ unsigned short f2bf(float f) {
  unsigned u = __builtin_bit_cast(unsigned, f);
  u += 0x7fffu + ((u >> 16) & 1u);
  return (unsigned short)(u >> 16);
}

__device__ __forceinline__ unsigned cvtpk(float lo, float hi) {
  unsigned r;
  asm("v_cvt_pk_bf16_f32 %0, %1, %2" : "=v"(r) : "v"(lo), "v"(hi));
  return r;
}

// ---------------------------------------------------------------------------
// Kernel 1: W [768][256] f32 -> Wt_tiled bf16: element (kt, h, col, e) =
// bf16(W[kt*32 + h*8 + e][col]).  Per-K-step image is 16KB; each lane's four
// B fragments are 16B chunks at 256B stride inside it (L1/L2-friendly).
// ---------------------------------------------------------------------------
__global__ __launch_bounds__(256) void wt_tile(const float* __restrict__ W,
                                               unsigned short* __restrict__ Wt) {
  __shared__ float Wl[32][257];     // +1 pad
  const int kt  = blockIdx.x;       // 0..23
  const int tid = threadIdx.x;

#pragma unroll
  for (int i = 0; i < 8; ++i) {
    const int idx = i * 256 + tid;          // 0..2047 chunks of f32x4
    const int row = idx >> 6;
    const int c4  = idx & 63;
    f32x4 v = *(const f32x4*)(W + (size_t)(kt * 32 + row) * N_DIM + c4 * 4);
    Wl[row][c4 * 4 + 0] = v[0];
    Wl[row][c4 * 4 + 1] = v[1];
    Wl[row][c4 * 4 + 2] = v[2];
    Wl[row][c4 * 4 + 3] = v[3];
  }
  __syncthreads();

#pragma unroll
  for (int h = 0; h < 4; ++h) {
    bf16x8 ov;
#pragma unroll
    for (int e = 0; e < 8; ++e) ov[e] = (short)f2bf(Wl[h * 8 + e][tid]);
    *(bf16x8*)(Wt + (((size_t)kt * 4 + h) * 256 + tid) * 8) = ov;
  }
}

// ---------------------------------------------------------------------------
// Kernel 2: GEMM + scatter + fused padding zero-fill.
//   blocks [0, NGEMM):    BM=32 GEMM tile
//   blocks [NGEMM, +240): zero 64 padding rows each (write-only, overlaps)
//
// Round-9 change (per-CU LDS BW was the limiter): B fragments are loaded
// DIRECTLY global->reg from L2-resident Wt_tiled each K-step (4 x dwordx4
// per lane, 256B segments) — B never touches LDS. A alone is LDS-staged
// (reg->cvt->ds_write bf16, XOR-permuted slots; 2KB per buffer).
// Per CU-step LDS traffic drops ~85% vs round 8.
// 256 threads = 4 waves; wave w owns cols w*64..+63 (2x4 frags, acc 32 VGPR).
// ---------------------------------------------------------------------------
__global__ __launch_bounds__(256, 4) void gemm_scatter(const float* __restrict__ A,
                                                       const unsigned short* __restrict__ Wt,
                                                       const float* __restrict__ bias,
                                                       float* __restrict__ out) {
  const int tid = threadIdx.x;

  // ---------------- fused zero-fill blocks ----------------
  if (blockIdx.x >= NGEMM) {
    const int z  = blockIdx.x - NGEMM;   // 0..239
    const int p0 = z * 64;               // global padding-row index
    int d = 0, c = 0;
    while (d < 15) {
      const int pad = 1920 - 128 * d;
      if (p0 < c + pad) break;
      c += pad; ++d;
    }
    const int len = 1024 + 128 * d;
    const size_t row0 = (size_t)d * MAXLEN + len + (p0 - c);
    float* dst = out + row0 * N_DIM;
    const f32x4 z4 = {0.f, 0.f, 0.f, 0.f};
#pragma unroll
    for (int j = 0; j < 16; ++j)
      *(f32x4*)(dst + (size_t)(j * 256 + tid) * 4) = z4;
    return;
  }

  // ---------------- GEMM blocks ----------------
  __shared__ f32x4 AbV[2][128];    // 2 x 2KB bf16 A image

  const int wid  = tid >> 6;       // 0..3 (N quarter)
  const int lane = tid & 63;
  const int l15  = lane & 15;
  const int l4   = lane >> 4;
  const int t0   = blockIdx.x * 32;

  // which doc does this tile live in (tiles never straddle docs)
  int off = 0, doc = 0;
  while (doc < 15) {
    const int len = 1024 + 128 * doc;
    if (t0 < off + len) break;
    off += len; ++doc;
  }
  const long tgt0 = (long)doc * MAXLEN + (t0 - off);

  // ---- A stage (threads < 128): row = t>>2 (0..31), g = t&3 (k-octet) ----
  const int rowS = (tid & 127) >> 2;
  const int gS   = tid & 3;
  const float* pA = A + (size_t)(t0 + rowS) * K_DIM + gS * 8;
  const int awbyte = (gS * 32 + (rowS ^ (gS << 1))) * 16;   // XOR-permuted slot

  // ---- B direct-load base: lane reads [h=l4][col] chunks of step image ----
  const int colB = wid * 64 + l15;
  const unsigned short* pB = Wt + ((size_t)l4 * 256 + colB) * 8;

  char* ldsA = (char*)&AbV[0][0];

  // ---- A fragment read offsets (row = m*16 + l15, k-octet = l4) ----
  const int aoff0 = l4 * 512 + ((l15 ^ (l4 << 1)) * 16);    // m=0; m=1 -> +256

  f32x4 acc[2][4];
#pragma unroll
  for (int m = 0; m < 2; ++m)
#pragma unroll
    for (int n = 0; n < 4; ++n) acc[m][n] = f32x4{0.f, 0.f, 0.f, 0.f};

#define WRITE_A(buf, La0, La1)                                           \
  {                                                                      \
    u32x4 u;                                                             \
    u[0] = cvtpk(La0[0], La0[1]); u[1] = cvtpk(La0[2], La0[3]);          \
    u[2] = cvtpk(La1[0], La1[1]); u[3] = cvtpk(La1[2], La1[3]);          \
    *(u32x4*)(ldsA + (buf) * 2048 + awbyte) = u;                         \
  }

  // prologue: stage A tile 0, barrier
  if (tid < 128) {
    f32x4 La0 = *(const f32x4*)(pA);
    f32x4 La1 = *(const f32x4*)(pA + 4);
    WRITE_A(0, La0, La1)
  }
  __syncthreads();

#pragma unroll 1
  for (int t = 0; t < NKT; ++t) {
    // B fragments for step t: direct from L2-resident Wt_tiled
    const unsigned short* pBt = pB + (size_t)t * 8192;
    bf16x8 b0 = *(const bf16x8*)(pBt);
    bf16x8 b1 = *(const bf16x8*)(pBt + 128);
    bf16x8 b2 = *(const bf16x8*)(pBt + 256);
    bf16x8 b3 = *(const bf16x8*)(pBt + 384);

    // A prefetch for step t+1 (in flight across the MFMAs)
    f32x4 La0, La1;
    if (t < NKT - 1 && tid < 128) {
      La0 = *(const f32x4*)(pA + (t + 1) * 32);
      La1 = *(const f32x4*)(pA + (t + 1) * 32 + 4);
    }

    // A fragments from LDS
    const char* ab = ldsA + (t & 1) * 2048;
    bf16x8 af0 = *(const bf16x8*)(ab + aoff0);
    bf16x8 af1 = *(const bf16x8*)(ab + aoff0 + 256);

    acc[0][0] = __builtin_amdgcn_mfma_f32_16x16x32_bf16(af0, b0, acc[0][0], 0, 0, 0);
    acc[0][1] = __builtin_amdgcn_mfma_f32_16x16x32_bf16(af0, b1, acc[0][1], 0, 0, 0);
    acc[0][2] = __builtin_amdgcn_mfma_f32_16x16x32_bf16(af0, b2, acc[0][2], 0, 0, 0);
    acc[0][3] = __builtin_amdgcn_mfma_f32_16x16x32_bf16(af0, b3, acc[0][3], 0, 0, 0);
    acc[1][0] = __builtin_amdgcn_mfma_f32_16x16x32_bf16(af1, b0, acc[1][0], 0, 0, 0);
    acc[1][1] = __builtin_amdgcn_mfma_f32_16x16x32_bf16(af1, b1, acc[1][1], 0, 0, 0);
    acc[1][2] = __builtin_amdgcn_mfma_f32_16x16x32_bf16(af1, b2, acc[1][2], 0, 0, 0);
    acc[1][3] = __builtin_amdgcn_mfma_f32_16x16x32_bf16(af1, b3, acc[1][3], 0, 0, 0);

    if (t < NKT - 1) {
      if (tid < 128) WRITE_A((t + 1) & 1, La0, La1)
      __syncthreads();
    }
  }

  // epilogue: bias + scatter to padded rows
  float bc[4];
#pragma unroll
  for (int n = 0; n < 4; ++n) bc[n] = bias[wid * 64 + n * 16 + l15];

#pragma unroll
  for (int m = 0; m < 2; ++m)
#pragma unroll
    for (int n = 0; n < 4; ++n) {
      const size_t base = (size_t)(tgt0 + m * 16 + l4 * 4) * N_DIM
                        + wid * 64 + n * 16 + l15;
#pragma unroll
      for (int j = 0; j < 4; ++j)
        out[base + (size_t)j * N_DIM] = acc[m][n][j] + bc[n];
    }
#undef WRITE_A
}

// ---------------------------------------------------------------------------
extern "C" void kernel_launch(void* const* d_in, const int* in_sizes, int n_in,
                              void* d_out, int out_size, void* d_ws, size_t ws_size,
                              hipStream_t stream) {
  const float* A    = (const float*)d_in[0];   // [31744, 768]
  const float* W    = (const float*)d_in[1];   // [768, 256]
  const float* bias = (const float*)d_in[2];   // [256]
  float* out = (float*)d_out;                  // [16, 2944, 256]
  unsigned short* Wt = (unsigned short*)d_ws;  // Wt_tiled bf16 [24][4][256][8]

  wt_tile<<<24, 256, 0, stream>>>(W, Wt);
  gemm_scatter<<<NGEMM + NZERO, 256, 0, stream>>>(A, Wt, bias, out);
}